// Round 9
// baseline (70600.696 us; speedup 1.0000x reference)
//
#include <hip/hip_runtime.h>
#include <hip/hip_cooperative_groups.h>
#include <hip/hip_bf16.h>
#include <math.h>

namespace cg = cooperative_groups;

#define B 64
#define T 128
#define S 128
#define E 512
#define H 1024
#define D 1024
#define KDIM 1024
#define G3 3072

__device__ __forceinline__ float sigmoidf_(float x) { return 1.f / (1.f + expf(-x)); }

// ---------------------------------------------------------------------------
// 128x128-tile f32 GEMM (proven R5/R8). SRC 0: plain A. SRC 1: rows (b,tl) ->
// reversed_input (K=512). SRC 2: rows (b,tl) -> [y_states|rnn_flip] (K=2048).
// ---------------------------------------------------------------------------
template<int SRC>
__global__ __launch_bounds__(256) void gemm128(
    const float* __restrict__ A1, const float* __restrict__ A2, int lda,
    const float* __restrict__ W, int ldw, const float* __restrict__ bias,
    float* __restrict__ C, int ldc, int Kd, int c0, int chLog) {
  __shared__ __align__(16) float As[16][132];
  __shared__ __align__(16) float Ws[16][132];
  const int bm = blockIdx.y * 128;
  const int bn = blockIdx.x * 128;
  const int tid = threadIdx.x;
  const int tr = tid >> 4, tc = tid & 15;
  float acc[8][8];
#pragma unroll
  for (int i = 0; i < 8; ++i)
#pragma unroll
    for (int j = 0; j < 8; ++j) acc[i][j] = 0.f;

  for (int k0 = 0; k0 < Kd; k0 += 16) {
#pragma unroll
    for (int l = 0; l < 8; ++l) {
      int i = tid + l * 256;
      int r = i >> 4, kk = i & 15;
      int rg = bm + r;
      int k = k0 + kk;
      float v;
      if (SRC == 0) {
        v = A1[(size_t)rg * lda + k];
      } else {
        int b = rg >> chLog, tl = rg & ((1 << chLog) - 1);
        int trow = b * T + c0 + tl;
        if (SRC == 1) v = A1[(size_t)trow * E + k];
        else v = (k < 1024) ? A1[(size_t)trow * 1024 + k]
                            : A2[(size_t)trow * 1024 + (k - 1024)];
      }
      As[kk][r] = v;
    }
#pragma unroll
    for (int l = 0; l < 8; ++l) {
      int i = tid + l * 256;
      int c = i >> 4, kk = i & 15;
      Ws[kk][c] = W[(size_t)(bn + c) * ldw + k0 + kk];
    }
    __syncthreads();
#pragma unroll
    for (int kk = 0; kk < 16; ++kk) {
      float a[8], w[8];
      *(float4*)&a[0] = *(const float4*)&As[kk][tr * 8];
      *(float4*)&a[4] = *(const float4*)&As[kk][tr * 8 + 4];
      *(float4*)&w[0] = *(const float4*)&Ws[kk][tc * 8];
      *(float4*)&w[4] = *(const float4*)&Ws[kk][tc * 8 + 4];
#pragma unroll
      for (int i = 0; i < 8; ++i)
#pragma unroll
        for (int j = 0; j < 8; ++j)
          acc[i][j] = fmaf(a[i], w[j], acc[i][j]);
    }
    __syncthreads();
  }
#pragma unroll
  for (int i = 0; i < 8; ++i) {
    int rg = bm + tr * 8 + i;
#pragma unroll
    for (int j = 0; j < 8; ++j) {
      int cc = bn + tc * 8 + j;
      float bv = bias ? bias[cc] : 0.f;
      C[(size_t)rg * ldc + cc] = acc[i][j] + bv;
    }
  }
}

// ---------------------------------------------------------------------------
// Scan-1 cooperative step-loop kernel: per step {gates(384 tasks) | GRU}.
// 512 thr/block. Phase impls mirror R8's proven kernels.
// ---------------------------------------------------------------------------
struct S1C {
  const float* gi; const float* Whh; const float* bhh;
  float* h; float* part; float* flip;
  int c0; int CH;
};

__global__ __launch_bounds__(512, 4) void scan1_coop(S1C a) {
  cg::grid_group grid = cg::this_grid();
  const int bid = blockIdx.x, NB = gridDim.x, tid = threadIdx.x;
  const int wv = tid >> 6, lane = tid & 63;
  __shared__ float smem[8 * 16 * 64];
  for (int tl = 0; tl < a.CH; ++tl) {
    const int t = a.c0 + tl;
    // ---- gates: gh = h @ Whh^T (2 segs x 192 jt) ----
    {
      float (*red16)[16][64] = (float(*)[16][64])smem;
      for (int task = bid; task < 384; task += NB) {
        int seg = task / 192, jt = task % 192;
        int j0 = jt * 16;
        const float* A = a.h + seg * 512;
        const float* W = a.Whh + seg * 512;
        float av[64];
        const float4* ap = (const float4*)(A + (size_t)lane * H + wv * 64);
#pragma unroll
        for (int q = 0; q < 16; ++q) {
          float4 v = ap[q];
          av[4*q] = v.x; av[4*q+1] = v.y; av[4*q+2] = v.z; av[4*q+3] = v.w;
        }
        float acc[16];
#pragma unroll
        for (int jj = 0; jj < 16; ++jj) {
          const float4* wp = (const float4*)(W + (size_t)(j0 + jj) * H + wv * 64);
          float s0 = 0.f, s1 = 0.f, s2 = 0.f, s3 = 0.f;
#pragma unroll
          for (int q = 0; q < 16; ++q) {
            float4 w = wp[q];
            s0 = fmaf(av[4*q],   w.x, s0);
            s1 = fmaf(av[4*q+1], w.y, s1);
            s2 = fmaf(av[4*q+2], w.z, s2);
            s3 = fmaf(av[4*q+3], w.w, s3);
          }
          acc[jj] = (s0 + s1) + (s2 + s3);
        }
#pragma unroll
        for (int jj = 0; jj < 16; ++jj) red16[wv][jj][lane] = acc[jj];
        __syncthreads();
        for (int idx = tid; idx < 1024; idx += 512) {
          int jj = idx >> 6, b = idx & 63;
          float v = 0.f;
#pragma unroll
          for (int w = 0; w < 8; ++w) v += red16[w][jj][b];
          a.part[((size_t)seg * G3 + j0 + jj) * 64 + b] = v;
        }
        __syncthreads();
      }
    }
    grid.sync();
    // ---- GRU (128 tasks x 8 j) ----
    {
      float (*st)[64] = (float(*)[64])smem;
      for (int task = bid; task < 128; task += NB) {
        int j0 = task * 8;
        int j = j0 + wv, b = lane;
        const float* gb = a.gi + (size_t)(b * a.CH + tl) * G3;
        float gir = gb[j], giz = gb[H + j], gin = gb[2 * H + j];
        float ghr = a.bhh[j], ghz = a.bhh[H + j], ghn = a.bhh[2 * H + j];
#pragma unroll
        for (int p2 = 0; p2 < 2; ++p2) {
          const float* pp = a.part + (size_t)p2 * G3 * 64;
          ghr += pp[(size_t)j * 64 + b];
          ghz += pp[(size_t)(H + j) * 64 + b];
          ghn += pp[(size_t)(2 * H + j) * 64 + b];
        }
        float r = sigmoidf_(gir + ghr);
        float z = sigmoidf_(giz + ghz);
        float n = tanhf(gin + r * ghn);
        float hnew = (1.f - z) * n + z * a.h[(size_t)b * H + j];
        st[wv][b] = hnew;
        __syncthreads();
        int jl = tid & 7, b2 = tid >> 3;
        float v = st[jl][b2];
        a.h[(size_t)b2 * H + j0 + jl] = v;
        a.flip[(size_t)b2 * T * H + (size_t)(T - 1 - t) * H + j0 + jl] = v;
        __syncthreads();
      }
    }
    grid.sync();
  }
}

// ---------------------------------------------------------------------------
// Scan-2 cooperative step-loop kernel: 6 phases per step.
// ---------------------------------------------------------------------------
struct S2C {
  const float* gi; const float* Wih; const float* Whh; const float* bhh;
  const float* corrW; const float* corrB; const float* qW;
  const float* avW; const float* avB;
  const float* rewW; const float* rewB; const float* eW;
  const float* pk; const float* enc;
  float* uv; float* h; float* part; float* ctx;
  float* pq; float* corrR; float* attH; float* rew; float* energ;
  float* oC; float* oR; float* oA;
  int c0; int CH;
};

__global__ __launch_bounds__(512, 4) void scan2_coop(S2C a) {
  cg::grid_group grid = cg::this_grid();
  const int bid = blockIdx.x, NB = gridDim.x, tid = threadIdx.x;
  const int wv = tid >> 6, lane = tid & 63;
  __shared__ float smem[8 * 16 * 64];   // 32 KB, aliased per phase
  for (int tl = 0; tl < a.CH; ++tl) {
    const int t = a.c0 + tl;

    // ---- phase 1: gates GEMM (uv K=2048 segs 0-3, h K=1024 segs 4-5) ----
    {
      float (*red16)[16][64] = (float(*)[16][64])smem;
      for (int task = bid; task < 1152; task += NB) {
        int seg = task / 192, jt = task % 192;
        int j0 = jt * 16;
        const float *A, *W; int lda, ldw;
        if (seg < 4) { A = a.uv + seg * 512; W = a.Wih + 2048 + seg * 512; lda = 2048; ldw = 4096; }
        else         { A = a.h + (seg - 4) * 512; W = a.Whh + (seg - 4) * 512; lda = 1024; ldw = 1024; }
        float av[64];
        const float4* ap = (const float4*)(A + (size_t)lane * lda + wv * 64);
#pragma unroll
        for (int q = 0; q < 16; ++q) {
          float4 v = ap[q];
          av[4*q] = v.x; av[4*q+1] = v.y; av[4*q+2] = v.z; av[4*q+3] = v.w;
        }
        float acc[16];
#pragma unroll
        for (int jj = 0; jj < 16; ++jj) {
          const float4* wp = (const float4*)(W + (size_t)(j0 + jj) * ldw + wv * 64);
          float s0 = 0.f, s1 = 0.f, s2 = 0.f, s3 = 0.f;
#pragma unroll
          for (int q = 0; q < 16; ++q) {
            float4 w = wp[q];
            s0 = fmaf(av[4*q],   w.x, s0);
            s1 = fmaf(av[4*q+1], w.y, s1);
            s2 = fmaf(av[4*q+2], w.z, s2);
            s3 = fmaf(av[4*q+3], w.w, s3);
          }
          acc[jj] = (s0 + s1) + (s2 + s3);
        }
#pragma unroll
        for (int jj = 0; jj < 16; ++jj) red16[wv][jj][lane] = acc[jj];
        __syncthreads();
        for (int idx = tid; idx < 1024; idx += 512) {
          int jj = idx >> 6, b = idx & 63;
          float v = 0.f;
#pragma unroll
          for (int w = 0; w < 8; ++w) v += red16[w][jj][b];
          a.part[((size_t)seg * G3 + j0 + jj) * 64 + b] = v;
        }
        __syncthreads();
      }
    }
    grid.sync();

    // ---- phase 2: GRU (128 tasks x 8 j) ----
    {
      float (*st)[64] = (float(*)[64])smem;
      for (int task = bid; task < 128; task += NB) {
        int j0 = task * 8;
        int j = j0 + wv, b = lane;
        const float* gb = a.gi + (size_t)(b * a.CH + tl) * G3;
        float gir = gb[j], giz = gb[H + j], gin = gb[2 * H + j];
#pragma unroll
        for (int p2 = 0; p2 < 4; ++p2) {
          const float* pp = a.part + (size_t)p2 * G3 * 64;
          gir += pp[(size_t)j * 64 + b];
          giz += pp[(size_t)(H + j) * 64 + b];
          gin += pp[(size_t)(2 * H + j) * 64 + b];
        }
        float ghr = a.bhh[j], ghz = a.bhh[H + j], ghn = a.bhh[2 * H + j];
#pragma unroll
        for (int p2 = 4; p2 < 6; ++p2) {
          const float* pp = a.part + (size_t)p2 * G3 * 64;
          ghr += pp[(size_t)j * 64 + b];
          ghz += pp[(size_t)(H + j) * 64 + b];
          ghn += pp[(size_t)(2 * H + j) * 64 + b];
        }
        float r = sigmoidf_(gir + ghr);
        float z = sigmoidf_(giz + ghz);
        float n = tanhf(gin + r * ghn);
        float hnew = (1.f - z) * n + z * a.h[(size_t)b * H + j];
        st[wv][b] = hnew;
        __syncthreads();
        int jl = tid & 7, b2 = tid >> 3;
        a.h[(size_t)b2 * H + j0 + jl] = st[jl][b2];
        __syncthreads();
      }
    }
    grid.sync();

    // ---- phase 3: h-projections (385 tasks, full K=1024 = 8 waves x 128) ----
    {
      float (*red8)[8][64] = (float(*)[8][64])smem;
      for (int task = bid; task < 385; task += NB) {
        const float* Wb; int ldw = 1024, n0, nrows, typ;
        if (task < 128)      { Wb = a.corrW; n0 = task * 8;         nrows = 8; typ = 0; }
        else if (task < 256) { Wb = a.qW;    n0 = (task - 128) * 8; nrows = 8; typ = 1; }
        else if (task < 384) { Wb = a.avW;   n0 = (task - 256) * 8; nrows = 8; typ = 2; ldw = 2048; }
        else                 { Wb = a.rewW;  n0 = 0;                nrows = 2; typ = 3; }
        const int k0 = wv * 128;
        const float* arow = a.h + (size_t)lane * H + k0;
        float acc[8] = {0.f, 0.f, 0.f, 0.f, 0.f, 0.f, 0.f, 0.f};
        for (int sc = 0; sc < 4; ++sc) {
          float av[32];
          const float4* ap = (const float4*)(arow + sc * 32);
#pragma unroll
          for (int q = 0; q < 8; ++q) {
            float4 v = ap[q];
            av[4*q] = v.x; av[4*q+1] = v.y; av[4*q+2] = v.z; av[4*q+3] = v.w;
          }
#pragma unroll
          for (int rr = 0; rr < 8; ++rr) {
            if (rr < nrows) {
              const float4* wp = (const float4*)(Wb + (size_t)(n0 + rr) * ldw + k0 + sc * 32);
              float s = acc[rr];
#pragma unroll
              for (int q = 0; q < 8; ++q) {
                float4 w = wp[q];
                s = fmaf(av[4*q],   w.x, s);
                s = fmaf(av[4*q+1], w.y, s);
                s = fmaf(av[4*q+2], w.z, s);
                s = fmaf(av[4*q+3], w.w, s);
              }
              acc[rr] = s;
            }
          }
        }
#pragma unroll
        for (int rr = 0; rr < 8; ++rr) red8[wv][rr][lane] = acc[rr];
        __syncthreads();
        {
          int jj = tid >> 6, b = tid & 63;   // 512 threads = exactly 8x64
          if (jj < nrows) {
            int n = n0 + jj;
            float v = 0.f;
#pragma unroll
            for (int w = 0; w < 8; ++w) v += red8[w][jj][b];
            if (typ == 0) a.corrR[(size_t)b * 1024 + n] = v + a.corrB[n];
            else if (typ == 1) a.pq[(size_t)b * 1024 + n] = v;
            else if (typ == 2) a.attH[(size_t)n * 64 + b] = v;
            else {
              float rv = v + a.rewB[n];
              a.rew[n * 64 + b] = rv;
              a.oR[((size_t)b * T + t) * 2 + n] = rv;
            }
          }
        }
        __syncthreads();
      }
    }
    grid.sync();

    // ---- phase 4: energies (8192 wave-tasks) ----
    {
      for (int task = bid * 8 + wv; task < 8192; task += NB * 8) {
        int b = task >> 7;
        const float* pkp = a.pk + (size_t)task * H;
        const float* qp = a.pq + (size_t)b * H;
        float acc = 0.f;
#pragma unroll
        for (int i = 0; i < 16; ++i) {
          int j = lane + i * 64;
          acc += tanhf(qp[j] + pkp[j]) * a.eW[j];
        }
#pragma unroll
        for (int off = 32; off > 0; off >>= 1) acc += __shfl_down(acc, off);
        if (lane == 0) a.energ[task] = acc;
      }
    }
    grid.sync();

    // ---- phase 5: softmax + context + corr finalize (128 tasks: b, half) ----
    {
      float* se = smem; float* sa = smem + 128; float* ss = smem + 256;
      for (int task = bid; task < 128; task += NB) {
        int b = task >> 1, half = task & 1;
        if (tid < 128) { float e = a.energ[b * S + tid]; se[tid] = e; sa[tid] = e; }
        __syncthreads();
        for (int st2 = 64; st2 > 0; st2 >>= 1) {
          if (tid < st2) sa[tid] = fmaxf(sa[tid], sa[tid + st2]);
          __syncthreads();
        }
        float mx = sa[0];
        __syncthreads();
        if (tid < 128) { float e2 = expf(se[tid] - mx); sa[tid] = e2; ss[tid] = e2; }
        __syncthreads();
        for (int st2 = 64; st2 > 0; st2 >>= 1) {
          if (tid < st2) ss[tid] += ss[tid + st2];
          __syncthreads();
        }
        float inv = 1.f / ss[0];
        __syncthreads();
        if (tid < 128) sa[tid] *= inv;
        __syncthreads();
        int k = half * 512 + tid;
        const float* eb = a.enc + (size_t)b * S * KDIM + k;
        float accc = 0.f;
#pragma unroll 8
        for (int s2 = 0; s2 < S; ++s2) accc = fmaf(sa[s2], eb[(size_t)s2 * KDIM], accc);
        a.ctx[(size_t)b * KDIM + k] = accc;
        float r0 = a.rew[b], r1 = a.rew[64 + b];
        float g = (r1 > r0) ? 0.f : 1.f;
        float cv = g * tanhf(a.corrR[(size_t)b * 1024 + k]);
        a.uv[(size_t)b * 2048 + k] = cv;
        a.oC[((size_t)b * T + t) * D + k] = cv;
        if (half == 0 && tid < 128) a.oA[((size_t)b * T + t) * S + tid] = sa[tid];
        __syncthreads();
      }
    }
    grid.sync();

    // ---- phase 6: attv ctx-half GEMM + combine (128 tasks) ----
    {
      float (*red8)[8][64] = (float(*)[8][64])smem;
      for (int task = bid; task < 128; task += NB) {
        int n0 = task * 8;
        const int k0 = wv * 128;
        const float* arow = a.ctx + (size_t)lane * KDIM + k0;
        float acc[8] = {0.f, 0.f, 0.f, 0.f, 0.f, 0.f, 0.f, 0.f};
        for (int sc = 0; sc < 4; ++sc) {
          float av[32];
          const float4* ap = (const float4*)(arow + sc * 32);
#pragma unroll
          for (int q = 0; q < 8; ++q) {
            float4 v = ap[q];
            av[4*q] = v.x; av[4*q+1] = v.y; av[4*q+2] = v.z; av[4*q+3] = v.w;
          }
#pragma unroll
          for (int jj = 0; jj < 8; ++jj) {
            const float4* wp = (const float4*)(a.avW + (size_t)(n0 + jj) * 2048 + 1024 + k0 + sc * 32);
            float s = acc[jj];
#pragma unroll
            for (int q = 0; q < 8; ++q) {
              float4 w = wp[q];
              s = fmaf(av[4*q],   w.x, s);
              s = fmaf(av[4*q+1], w.y, s);
              s = fmaf(av[4*q+2], w.z, s);
              s = fmaf(av[4*q+3], w.w, s);
            }
            acc[jj] = s;
          }
        }
#pragma unroll
        for (int jj = 0; jj < 8; ++jj) red8[wv][jj][lane] = acc[jj];
        __syncthreads();
        {
          int jj = tid >> 6, bb = tid & 63;
          int n = n0 + jj;
          float v = 0.f;
#pragma unroll
          for (int w = 0; w < 8; ++w) v += red8[w][jj][bb];
          v += a.attH[(size_t)n * 64 + bb] + a.avB[n];
          a.uv[(size_t)bb * 2048 + 1024 + n] = tanhf(v);
        }
        __syncthreads();
      }
    }
    grid.sync();
  }
}

extern "C" void kernel_launch(void* const* d_in, const int* in_sizes, int n_in,
                              void* d_out, int out_size, void* d_ws, size_t ws_size,
                              hipStream_t stream) {
  const float* reversed_input = (const float*)d_in[0];
  const float* y_states = (const float*)d_in[3];
  const float* encoder = (const float*)d_in[4];
  const float* rnn_Wih = (const float*)d_in[6];
  const float* rnn_Whh = (const float*)d_in[7];
  const float* rnn_bih = (const float*)d_in[8];
  const float* rnn_bhh = (const float*)d_in[9];
  const float* out_Wih = (const float*)d_in[10];
  const float* out_Whh = (const float*)d_in[11];
  const float* out_bih = (const float*)d_in[12];
  const float* out_bhh = (const float*)d_in[13];
  const float* corr_W = (const float*)d_in[14];
  const float* corr_b = (const float*)d_in[15];
  const float* reward_W = (const float*)d_in[16];
  const float* reward_b = (const float*)d_in[17];
  const float* attv_W = (const float*)d_in[18];
  const float* attv_b = (const float*)d_in[19];
  const float* key_W = (const float*)d_in[20];
  const float* query_W = (const float*)d_in[21];
  const float* energy_W = (const float*)d_in[22];

  float* out_corrs = (float*)d_out;                    // (B,T,D)
  float* out_rewards = out_corrs + (size_t)B * T * D;  // (B,T,2)
  float* out_attns = out_rewards + (size_t)B * T * 2;  // (B,T,S)

  // workspace (floats)
  float* p = (float*)d_ws;
  float* rnn_flip = p;  p += (size_t)B * T * H;
  float* proj_keys = p; p += (size_t)B * S * H;
  float* part = p;      p += (size_t)6 * G3 * 64;
  float* h = p;         p += (size_t)B * H;
  float* uv = p;        p += (size_t)B * 2048;
  float* ctx = p;       p += (size_t)B * KDIM;
  float* corrR = p;     p += (size_t)B * 1024;
  float* pq = p;        p += (size_t)B * H;
  float* attH = p;      p += (size_t)H * 64;
  float* rew = p;       p += 128;
  float* energ = p;     p += (size_t)B * S;
  size_t fixedF = (size_t)(p - (float*)d_ws);
  // CH capped at 16 so the scan-2 hot set (~140 MB) stays L3-resident.
  int CH = 8, chLog = 3;
  if (ws_size >= (fixedF + 16ull * 64 * G3) * 4) { CH = 16; chLog = 4; }
  float* gibuf = p;  // CH*64 rows x G3, row-major [(b*CH+tl)][G3]

  int mp = 256;
  {
    hipDeviceProp_t prop;
    int dev = 0;
    if (hipGetDevice(&dev) == hipSuccess && hipGetDeviceProperties(&prop, dev) == hipSuccess)
      mp = prop.multiProcessorCount;
  }
  int ob1 = 0, ob2 = 0;
  if (hipOccupancyMaxActiveBlocksPerMultiprocessor(&ob1, (const void*)scan1_coop, 512, 0) != hipSuccess || ob1 < 1) ob1 = 1;
  if (hipOccupancyMaxActiveBlocksPerMultiprocessor(&ob2, (const void*)scan2_coop, 512, 0) != hipSuccess || ob2 < 1) ob2 = 1;
  int NB1 = ob1 * mp; if (NB1 > 512) NB1 = 512;
  int NB2 = ob2 * mp; if (NB2 > 512) NB2 = 512;

  dim3 blk256(256), blk512(512);

  // proj_keys = encoder @ key_W^T
  gemm128<0><<<dim3(H / 128, (B * S) / 128), blk256, 0, stream>>>(
      encoder, nullptr, KDIM, key_W, KDIM, nullptr, proj_keys, H, KDIM, 0, 0);

  // ---- scan 1 ----
  hipMemsetAsync(h, 0, (size_t)B * H * sizeof(float), stream);
  for (int c0 = 0; c0 < T; c0 += CH) {
    gemm128<1><<<dim3(G3 / 128, (64 * CH) / 128), blk256, 0, stream>>>(
        reversed_input, nullptr, 0, rnn_Wih, E, rnn_bih, gibuf, G3, E, c0, chLog);
    S1C s1;
    s1.gi = gibuf; s1.Whh = rnn_Whh; s1.bhh = rnn_bhh;
    s1.h = h; s1.part = part; s1.flip = rnn_flip; s1.c0 = c0; s1.CH = CH;
    void* kp1[] = {&s1};
    hipLaunchCooperativeKernel((void*)scan1_coop, dim3(NB1), blk512, kp1, 0, stream);
  }

  // ---- scan 2 ----
  hipMemsetAsync(h, 0, (size_t)B * H * sizeof(float), stream);
  hipMemsetAsync(uv, 0, (size_t)B * 2048 * sizeof(float), stream);
  for (int c0 = 0; c0 < T; c0 += CH) {
    gemm128<2><<<dim3(G3 / 128, (64 * CH) / 128), blk256, 0, stream>>>(
        y_states, rnn_flip, 0, out_Wih, 4096, out_bih, gibuf, G3, 2048, c0, chLog);
    S2C s2;
    s2.gi = gibuf; s2.Wih = out_Wih; s2.Whh = out_Whh; s2.bhh = out_bhh;
    s2.corrW = corr_W; s2.corrB = corr_b; s2.qW = query_W;
    s2.avW = attv_W; s2.avB = attv_b;
    s2.rewW = reward_W; s2.rewB = reward_b; s2.eW = energy_W;
    s2.pk = proj_keys; s2.enc = encoder;
    s2.uv = uv; s2.h = h; s2.part = part; s2.ctx = ctx;
    s2.pq = pq; s2.corrR = corrR; s2.attH = attH; s2.rew = rew; s2.energ = energ;
    s2.oC = out_corrs; s2.oR = out_rewards; s2.oA = out_attns;
    s2.c0 = c0; s2.CH = CH;
    void* kp2[] = {&s2};
    hipLaunchCooperativeKernel((void*)scan2_coop, dim3(NB2), blk512, kp2, 0, stream);
  }
}

// Round 10
// 23026.349 us; speedup vs baseline: 3.0661x; 3.0661x over previous
//
#include <hip/hip_runtime.h>
#include <hip/hip_bf16.h>
#include <math.h>

#define B 64
#define T 128
#define S 128
#define E 512
#define H 1024
#define D 1024
#define KDIM 1024
#define G3 3072
#define JT 16

__device__ __forceinline__ float sigmoidf_(float x) { return 1.f / (1.f + expf(-x)); }

// ---------------------------------------------------------------------------
// 128x128-tile f32 GEMM (proven R5/R8/R9). SRC 0: plain A. SRC 1: rows (b,tl)
// -> reversed_input (K=512). SRC 2: rows (b,tl) -> [y_states|rnn_flip] (K=2048).
// ---------------------------------------------------------------------------
template<int SRC>
__global__ __launch_bounds__(256) void gemm128(
    const float* __restrict__ A1, const float* __restrict__ A2, int lda,
    const float* __restrict__ W, int ldw, const float* __restrict__ bias,
    float* __restrict__ C, int ldc, int Kd, int c0, int chLog) {
  __shared__ __align__(16) float As[16][132];
  __shared__ __align__(16) float Ws[16][132];
  const int bm = blockIdx.y * 128;
  const int bn = blockIdx.x * 128;
  const int tid = threadIdx.x;
  const int tr = tid >> 4, tc = tid & 15;
  float acc[8][8];
#pragma unroll
  for (int i = 0; i < 8; ++i)
#pragma unroll
    for (int j = 0; j < 8; ++j) acc[i][j] = 0.f;

  for (int k0 = 0; k0 < Kd; k0 += 16) {
#pragma unroll
    for (int l = 0; l < 8; ++l) {
      int i = tid + l * 256;
      int r = i >> 4, kk = i & 15;
      int rg = bm + r;
      int k = k0 + kk;
      float v;
      if (SRC == 0) {
        v = A1[(size_t)rg * lda + k];
      } else {
        int b = rg >> chLog, tl = rg & ((1 << chLog) - 1);
        int trow = b * T + c0 + tl;
        if (SRC == 1) v = A1[(size_t)trow * E + k];
        else v = (k < 1024) ? A1[(size_t)trow * 1024 + k]
                            : A2[(size_t)trow * 1024 + (k - 1024)];
      }
      As[kk][r] = v;
    }
#pragma unroll
    for (int l = 0; l < 8; ++l) {
      int i = tid + l * 256;
      int c = i >> 4, kk = i & 15;
      Ws[kk][c] = W[(size_t)(bn + c) * ldw + k0 + kk];
    }
    __syncthreads();
#pragma unroll
    for (int kk = 0; kk < 16; ++kk) {
      float a[8], w[8];
      *(float4*)&a[0] = *(const float4*)&As[kk][tr * 8];
      *(float4*)&a[4] = *(const float4*)&As[kk][tr * 8 + 4];
      *(float4*)&w[0] = *(const float4*)&Ws[kk][tc * 8];
      *(float4*)&w[4] = *(const float4*)&Ws[kk][tc * 8 + 4];
#pragma unroll
      for (int i = 0; i < 8; ++i)
#pragma unroll
        for (int j = 0; j < 8; ++j)
          acc[i][j] = fmaf(a[i], w[j], acc[i][j]);
    }
    __syncthreads();
  }
#pragma unroll
  for (int i = 0; i < 8; ++i) {
    int rg = bm + tr * 8 + i;
#pragma unroll
    for (int j = 0; j < 8; ++j) {
      int cc = bn + tc * 8 + j;
      float bv = bias ? bias[cc] : 0.f;
      C[(size_t)rg * ldc + cc] = acc[i][j] + bv;
    }
  }
}

// ---------------------------------------------------------------------------
// Scalar-broadcast skinny GEMM (proven R2-R8). NEW: partials stored [seg][b][j]
// (row length Nstr) so the GRU consumer reads lane=j coalesced.
// ---------------------------------------------------------------------------
struct SBSeg { const float* A; const float* W; int lda; int ldw; int N; };
struct SBArgs { SBSeg s[6]; };

__global__ __launch_bounds__(256) void sb_gemm(SBArgs args, int jtPerSeg, int Nstr,
                                               float* __restrict__ part) {
  const int seg = blockIdx.x / jtPerSeg;
  const int jt = blockIdx.x % jtPerSeg;
  const SBSeg sg = args.s[seg];
  const int j0 = jt * JT;
  if (j0 >= sg.N) return;
  const int wv = __builtin_amdgcn_readfirstlane(threadIdx.x >> 6);
  const int lane = threadIdx.x & 63;
  float a[128];
  const float4* ap = (const float4*)(sg.A + (size_t)lane * sg.lda + wv * 128);
#pragma unroll
  for (int q = 0; q < 32; ++q) {
    float4 v = ap[q];
    a[q * 4 + 0] = v.x; a[q * 4 + 1] = v.y; a[q * 4 + 2] = v.z; a[q * 4 + 3] = v.w;
  }
  float acc[JT];
#pragma unroll
  for (int jj = 0; jj < JT; ++jj) acc[jj] = 0.f;
#pragma unroll
  for (int jj = 0; jj < JT; ++jj) {
    int j = j0 + jj;
    if (j < sg.N) {
      const float4* wp = (const float4*)(sg.W + (size_t)j * sg.ldw + wv * 128);
      float s0 = 0.f, s1 = 0.f, s2 = 0.f, s3 = 0.f;
#pragma unroll
      for (int q = 0; q < 32; ++q) {
        float4 w4 = wp[q];
        s0 = fmaf(a[q * 4 + 0], w4.x, s0);
        s1 = fmaf(a[q * 4 + 1], w4.y, s1);
        s2 = fmaf(a[q * 4 + 2], w4.z, s2);
        s3 = fmaf(a[q * 4 + 3], w4.w, s3);
      }
      acc[jj] = (s0 + s1) + (s2 + s3);
    }
  }
  __shared__ float red[4][JT][64];
#pragma unroll
  for (int jj = 0; jj < JT; ++jj) red[wv][jj][lane] = acc[jj];
  __syncthreads();
  // write [seg][b][j0+jj]: 16 consecutive floats per b (full 64B line)
  for (int idx = threadIdx.x; idx < JT * 64; idx += 256) {
    int b = idx >> 4, jj = idx & 15;
    int j = j0 + jj;
    if (j < sg.N) {
      float v = red[0][jj][b] + red[1][jj][b] + red[2][jj][b] + red[3][jj][b];
      part[((size_t)seg * 64 + b) * Nstr + j] = v;
    }
  }
}

// ---------------------------------------------------------------------------
// GRU cell, fully coalesced: block = (b, j-cluster of 256). gi row-major
// [b*CH+tl][G3]; partials [seg][b][G3]; h row-major. No LDS, no syncthreads.
// Grid 256 x 256 thr.
// ---------------------------------------------------------------------------
__global__ __launch_bounds__(256) void gru_reduce(
    const float* __restrict__ part, const float* __restrict__ gi,
    int CH, int tl, int nsGi, int ghStart, int nsGh,
    const float* __restrict__ bhh, float* __restrict__ hrow,
    float* __restrict__ flip_out, int t) {
  const int b = blockIdx.x >> 2;
  const int j = (blockIdx.x & 3) * 256 + threadIdx.x;
  const float* gb = gi + (size_t)(b * CH + tl) * G3;
  float gir = gb[j];
  float giz = gb[H + j];
  float gin = gb[2 * H + j];
  for (int p2 = 0; p2 < nsGi; ++p2) {
    const float* pp = part + ((size_t)p2 * 64 + b) * G3;
    gir += pp[j]; giz += pp[H + j]; gin += pp[2 * H + j];
  }
  float ghr = bhh[j], ghz = bhh[H + j], ghn = bhh[2 * H + j];
  for (int p2 = ghStart; p2 < ghStart + nsGh; ++p2) {
    const float* pp = part + ((size_t)p2 * 64 + b) * G3;
    ghr += pp[j]; ghz += pp[H + j]; ghn += pp[2 * H + j];
  }
  float r = sigmoidf_(gir + ghr);
  float z = sigmoidf_(giz + ghz);
  float n = tanhf(gin + r * ghn);
  float hold = hrow[(size_t)b * H + j];
  float hnew = (1.f - z) * n + z * hold;
  hrow[(size_t)b * H + j] = hnew;
  if (flip_out)
    flip_out[(size_t)b * T * H + (size_t)(T - 1 - t) * H + j] = hnew;
}

// ---------------------------------------------------------------------------
// h-projections, full K=1024 in-block (4 waves x 256). Grid 385 (R8-proven).
// Write mapping n-fastest for corrR/pq (32B segments).
// ---------------------------------------------------------------------------
__global__ __launch_bounds__(256) void hproj_gemm(
    const float* __restrict__ h,
    const float* __restrict__ corrW, const float* __restrict__ corrB,
    const float* __restrict__ qW, const float* __restrict__ avW,
    const float* __restrict__ rewW, const float* __restrict__ rewB,
    float* __restrict__ corrR, float* __restrict__ pq,
    float* __restrict__ attH, float* __restrict__ rew,
    float* __restrict__ out_rewards, int t) {
  const int task = blockIdx.x;
  const int tid = threadIdx.x;
  const int wv = __builtin_amdgcn_readfirstlane(tid >> 6);
  const int lane = tid & 63;
  const float* Wb; int ldw = 1024, n0, nrows, typ;
  if (task < 128)      { Wb = corrW; n0 = task * 8;         nrows = 8; typ = 0; }
  else if (task < 256) { Wb = qW;    n0 = (task - 128) * 8; nrows = 8; typ = 1; }
  else if (task < 384) { Wb = avW;   n0 = (task - 256) * 8; nrows = 8; typ = 2; ldw = 2048; }
  else                 { Wb = rewW;  n0 = 0;                nrows = 2; typ = 3; }
  const int k0 = wv * 256;
  const float* arow = h + (size_t)lane * H + k0;
  float acc[8] = {0.f, 0.f, 0.f, 0.f, 0.f, 0.f, 0.f, 0.f};
  for (int sc = 0; sc < 8; ++sc) {
    float av[32];
    const float4* ap = (const float4*)(arow + sc * 32);
#pragma unroll
    for (int q = 0; q < 8; ++q) {
      float4 v = ap[q];
      av[4*q] = v.x; av[4*q+1] = v.y; av[4*q+2] = v.z; av[4*q+3] = v.w;
    }
#pragma unroll
    for (int rr = 0; rr < 8; ++rr) {
      if (rr < nrows) {
        const float4* wp = (const float4*)(Wb + (size_t)(n0 + rr) * ldw + k0 + sc * 32);
        float s = acc[rr];
#pragma unroll
        for (int q = 0; q < 8; ++q) {
          float4 w = wp[q];
          s = fmaf(av[4*q],   w.x, s);
          s = fmaf(av[4*q+1], w.y, s);
          s = fmaf(av[4*q+2], w.z, s);
          s = fmaf(av[4*q+3], w.w, s);
        }
        acc[rr] = s;
      }
    }
  }
  __shared__ float red[4][8][64];
#pragma unroll
  for (int rr = 0; rr < 8; ++rr) red[wv][rr][lane] = acc[rr];
  __syncthreads();
  for (int idx = tid; idx < 512; idx += 256) {
    int b = idx >> 3, jj = idx & 7;   // n-fastest within each b
    if (jj < nrows) {
      int n = n0 + jj;
      float v = red[0][jj][b] + red[1][jj][b] + red[2][jj][b] + red[3][jj][b];
      if (typ == 0) corrR[(size_t)b * 1024 + n] = v + corrB[n];
      else if (typ == 1) pq[(size_t)b * 1024 + n] = v;
      else if (typ == 2) attH[(size_t)n * 64 + b] = v;
      else {
        float rv = v + rewB[n];
        rew[n * 64 + b] = rv;
        out_rewards[((size_t)b * T + t) * 2 + n] = rv;
      }
    }
  }
}

// energies: wave per (b,s). Grid 2048 x 256. (R3/R8-proven verbatim.)
__global__ __launch_bounds__(256) void energy_kernel(
    const float* __restrict__ pq, const float* __restrict__ pk,
    const float* __restrict__ eW, float* __restrict__ energies) {
  int wid = blockIdx.x * 4 + (threadIdx.x >> 6);
  int lane = threadIdx.x & 63;
  int b = wid >> 7, s = wid & 127;
  const float* pkp = pk + ((size_t)b * S + s) * H;
  const float* qp = pq + (size_t)b * H;
  float acc = 0.f;
#pragma unroll
  for (int i = 0; i < 16; ++i) {
    int j = lane + i * 64;
    acc += tanhf(qp[j] + pkp[j]) * eW[j];
  }
#pragma unroll
  for (int off = 32; off > 0; off >>= 1) acc += __shfl_down(acc, off);
  if (lane == 0) energies[b * S + s] = acc;
}

// Softmax (redundant per kt) + context + corr finalize + outputs.
// Grid (64, 4) x 256. (R8-proven verbatim.)
__global__ __launch_bounds__(256) void smct_plus(
    const float* __restrict__ energies, const float* __restrict__ enc,
    const float* __restrict__ corrR, const float* __restrict__ rew,
    float* __restrict__ ctx, float* __restrict__ uv,
    float* __restrict__ out_attns, float* __restrict__ out_corrs, int t) {
  int b = blockIdx.x, kt = blockIdx.y;
  int tid = threadIdx.x;
  __shared__ float se[128], sa[128], ss[128];
  if (tid < 128) { se[tid] = energies[b * S + tid]; sa[tid] = se[tid]; }
  __syncthreads();
  for (int st2 = 64; st2 > 0; st2 >>= 1) {
    if (tid < st2) sa[tid] = fmaxf(sa[tid], sa[tid + st2]);
    __syncthreads();
  }
  float mx = sa[0];
  __syncthreads();
  if (tid < 128) { sa[tid] = expf(se[tid] - mx); ss[tid] = sa[tid]; }
  __syncthreads();
  for (int st2 = 64; st2 > 0; st2 >>= 1) {
    if (tid < st2) ss[tid] += ss[tid + st2];
    __syncthreads();
  }
  float inv = 1.f / ss[0];
  __syncthreads();
  if (tid < 128) sa[tid] *= inv;
  __syncthreads();
  int k = kt * 256 + tid;
  const float* eb = enc + (size_t)b * S * KDIM + k;
  float acc = 0.f;
#pragma unroll 4
  for (int s2 = 0; s2 < S; ++s2) acc = fmaf(sa[s2], eb[(size_t)s2 * KDIM], acc);
  ctx[(size_t)b * KDIM + k] = acc;
  float r0 = rew[b], r1 = rew[64 + b];
  float g = (r1 > r0) ? 0.f : 1.f;
  float cv = g * tanhf(corrR[(size_t)b * 1024 + k]);
  uv[(size_t)b * 2048 + k] = cv;
  out_corrs[((size_t)b * T + t) * D + k] = cv;
  if (kt == 0 && tid < 128) out_attns[((size_t)b * T + t) * S + tid] = sa[tid];
}

// attv ctx-half GEMM + attH + bias + tanh -> uv att-half. Grid 128 x 256.
// (R8-proven verbatim.)
__global__ __launch_bounds__(256) void final_attv(
    const float* __restrict__ attH, const float* __restrict__ avW,
    const float* __restrict__ avB, const float* __restrict__ ctx,
    float* __restrict__ uv) {
  const int n0 = blockIdx.x * 8;
  const int tid = threadIdx.x;
  const int wv = __builtin_amdgcn_readfirstlane(tid >> 6);
  const int lane = tid & 63;
  __shared__ float red[4][8][64];
  float acc[8];
#pragma unroll
  for (int jj = 0; jj < 8; ++jj) acc[jj] = 0.f;
  const int k0 = wv * 256;
  const float* arow = ctx + (size_t)lane * KDIM + k0;
  for (int sc = 0; sc < 8; ++sc) {
    float av[32];
    const float4* ap = (const float4*)(arow + sc * 32);
#pragma unroll
    for (int q = 0; q < 8; ++q) {
      float4 v = ap[q];
      av[4*q] = v.x; av[4*q+1] = v.y; av[4*q+2] = v.z; av[4*q+3] = v.w;
    }
#pragma unroll
    for (int jj = 0; jj < 8; ++jj) {
      const float4* wp = (const float4*)(avW + (size_t)(n0 + jj) * 2048 + 1024 + k0 + sc * 32);
      float s = acc[jj];
#pragma unroll
      for (int q = 0; q < 8; ++q) {
        float4 w = wp[q];
        s = fmaf(av[4*q],   w.x, s);
        s = fmaf(av[4*q+1], w.y, s);
        s = fmaf(av[4*q+2], w.z, s);
        s = fmaf(av[4*q+3], w.w, s);
      }
      acc[jj] = s;
    }
  }
#pragma unroll
  for (int jj = 0; jj < 8; ++jj) red[wv][jj][lane] = acc[jj];
  __syncthreads();
  for (int idx = tid; idx < 512; idx += 256) {
    int jj = idx >> 6, bb = idx & 63;
    int n = n0 + jj;
    float v = red[0][jj][bb] + red[1][jj][bb] + red[2][jj][bb] + red[3][jj][bb]
            + attH[(size_t)n * 64 + bb] + avB[n];
    uv[(size_t)bb * 2048 + 1024 + n] = tanhf(v);
  }
}

extern "C" void kernel_launch(void* const* d_in, const int* in_sizes, int n_in,
                              void* d_out, int out_size, void* d_ws, size_t ws_size,
                              hipStream_t stream) {
  const float* reversed_input = (const float*)d_in[0];
  const float* y_states = (const float*)d_in[3];
  const float* encoder = (const float*)d_in[4];
  const float* rnn_Wih = (const float*)d_in[6];
  const float* rnn_Whh = (const float*)d_in[7];
  const float* rnn_bih = (const float*)d_in[8];
  const float* rnn_bhh = (const float*)d_in[9];
  const float* out_Wih = (const float*)d_in[10];
  const float* out_Whh = (const float*)d_in[11];
  const float* out_bih = (const float*)d_in[12];
  const float* out_bhh = (const float*)d_in[13];
  const float* corr_W = (const float*)d_in[14];
  const float* corr_b = (const float*)d_in[15];
  const float* reward_W = (const float*)d_in[16];
  const float* reward_b = (const float*)d_in[17];
  const float* attv_W = (const float*)d_in[18];
  const float* attv_b = (const float*)d_in[19];
  const float* key_W = (const float*)d_in[20];
  const float* query_W = (const float*)d_in[21];
  const float* energy_W = (const float*)d_in[22];

  float* out_corrs = (float*)d_out;                    // (B,T,D)
  float* out_rewards = out_corrs + (size_t)B * T * D;  // (B,T,2)
  float* out_attns = out_rewards + (size_t)B * T * 2;  // (B,T,S)

  // workspace (floats)
  float* p = (float*)d_ws;
  float* rnn_flip = p;  p += (size_t)B * T * H;        // [b][t][j]
  float* proj_keys = p; p += (size_t)B * S * H;
  float* part = p;      p += (size_t)6 * 64 * G3;      // [seg][b][j]
  float* h = p;         p += (size_t)B * H;
  float* uv = p;        p += (size_t)B * 2048;
  float* ctx = p;       p += (size_t)B * KDIM;
  float* corrR = p;     p += (size_t)B * 1024;
  float* pq = p;        p += (size_t)B * H;
  float* attH = p;      p += (size_t)H * 64;
  float* rew = p;       p += 128;
  float* energ = p;     p += (size_t)B * S;
  size_t fixedF = (size_t)(p - (float*)d_ws);
  int CH = 8, chLog = 3;
  {
    int c = 64, l = 6;
    for (; c >= 8; c >>= 1, --l)
      if (ws_size >= (fixedF + (size_t)c * 64 * G3) * 4) break;
    if (c < 8) { c = 8; l = 3; }
    CH = c; chLog = l;
  }
  float* gibuf = p;  // [b*CH+tl][G3] row-major

  hipMemsetAsync(h, 0, (size_t)B * H * sizeof(float), stream);
  hipMemsetAsync(uv, 0, (size_t)B * 2048 * sizeof(float), stream);

  dim3 blk(256);

  // proj_keys = encoder @ key_W^T
  gemm128<0><<<dim3(H / 128, (B * S) / 128), blk, 0, stream>>>(
      encoder, nullptr, KDIM, key_W, KDIM, nullptr, proj_keys, H, KDIM, 0, 0);

  // ---- scan 1: backward GRU (2 launches/step) ----
  for (int c0 = 0; c0 < T; c0 += CH) {
    gemm128<1><<<dim3(G3 / 128, (64 * CH) / 128), blk, 0, stream>>>(
        reversed_input, nullptr, 0, rnn_Wih, E, rnn_bih, gibuf, G3, E, c0, chLog);
    for (int tl = 0; tl < CH; ++tl) {
      int t = c0 + tl;
      SBArgs s1{};
      s1.s[0] = { h, rnn_Whh, H, H, G3 };
      s1.s[1] = { h + 512, rnn_Whh + 512, H, H, G3 };
      sb_gemm<<<2 * 192, blk, 0, stream>>>(s1, 192, G3, part);
      gru_reduce<<<256, blk, 0, stream>>>(part, gibuf, CH, tl, 0, 0, 2,
                                          rnn_bhh, h, rnn_flip, t);
    }
  }

  // ---- scan 2: output GRU + attention (6 launches/step) ----
  hipMemsetAsync(h, 0, (size_t)B * H * sizeof(float), stream);
  for (int c0 = 0; c0 < T; c0 += CH) {
    gemm128<2><<<dim3(G3 / 128, (64 * CH) / 128), blk, 0, stream>>>(
        y_states, rnn_flip, 0, out_Wih, 4096, out_bih, gibuf, G3, 2048, c0, chLog);
    for (int tl = 0; tl < CH; ++tl) {
      int t = c0 + tl;
      // 1) gates GEMM: gi(uv, K=2048, segs 0-3) + gh(h, K=1024, segs 4-5)
      SBArgs k1{};
      for (int s2 = 0; s2 < 4; ++s2)
        k1.s[s2] = { uv + s2 * 512, out_Wih + 2048 + s2 * 512, 2048, 4096, G3 };
      for (int s2 = 0; s2 < 2; ++s2)
        k1.s[4 + s2] = { h + s2 * 512, out_Whh + s2 * 512, H, H, G3 };
      sb_gemm<<<6 * 192, blk, 0, stream>>>(k1, 192, G3, part);
      // 2) GRU cell
      gru_reduce<<<256, blk, 0, stream>>>(part, gibuf, CH, tl, 4, 4, 2,
                                          out_bhh, h, nullptr, t);
      // 3) h-projections (full K in-block, final values)
      hproj_gemm<<<385, blk, 0, stream>>>(h, corr_W, corr_b, query_W, attv_W,
                                          reward_W, reward_b, corrR, pq, attH,
                                          rew, out_rewards, t);
      // 4) energies
      energy_kernel<<<2048, blk, 0, stream>>>(pq, proj_keys, energy_W, energ);
      // 5) softmax + context + corr finalize + outputs
      smct_plus<<<dim3(B, 4), blk, 0, stream>>>(energ, encoder, corrR, rew,
                                                ctx, uv, out_attns, out_corrs, t);
      // 6) attv ctx-half + combine -> uv att-half
      final_attv<<<128, blk, 0, stream>>>(attH, attv_W, attv_b, ctx, uv);
    }
  }
}